// Round 1
// baseline (980.193 us; speedup 1.0000x reference)
//
#include <hip/hip_runtime.h>
#include <math.h>

#define N_IN_F 28
#define N_HID 16
#define N_OUT 2

// ---------------- kernels ----------------

__global__ void k_init_deg(float* __restrict__ deg, int n) {
    int i = blockIdx.x * blockDim.x + threadIdx.x;
    if (i < n) deg[i] = 1.0f;  // self-loop contributes 1 to every node's degree
}

__global__ void k_deg(const int* __restrict__ dst, float* __restrict__ deg, int ne) {
    int e = blockIdx.x * blockDim.x + threadIdx.x;
    if (e < ne) atomicAdd(&deg[dst[e]], 1.0f);
}

// per-node: dis = rsqrt(deg); h1 = x @ W1; hs1 = h1*dis; acc1 = hs1 (self-loop seed)
__global__ void k_h1(const float* __restrict__ x, const float* __restrict__ W1,
                     float* __restrict__ deg_dis, float* __restrict__ hs1,
                     float* __restrict__ acc1, int n) {
    __shared__ float w[N_IN_F * N_HID];
    for (int t = threadIdx.x; t < N_IN_F * N_HID; t += blockDim.x) w[t] = W1[t];
    __syncthreads();
    int i = blockIdx.x * blockDim.x + threadIdx.x;
    if (i >= n) return;

    float xi[N_IN_F];
    const float* xr = x + (size_t)i * N_IN_F;
#pragma unroll
    for (int k = 0; k < N_IN_F; ++k) xi[k] = xr[k];

    float d = deg_dis[i];
    float dis = rsqrtf(d);   // deg >= 1 always (self-loop)
    deg_dis[i] = dis;

    float* hs = hs1 + (size_t)i * N_HID;
    float* ac = acc1 + (size_t)i * N_HID;
#pragma unroll
    for (int f = 0; f < N_HID; ++f) {
        float h = 0.0f;
#pragma unroll
        for (int k = 0; k < N_IN_F; ++k) h = fmaf(xi[k], w[k * N_HID + f], h);
        float v = h * dis;
        hs[f] = v;
        ac[f] = v;
    }
}

// per-(edge, f): acc1[dst*16+f] += hs1[src*16+f]
__global__ void k_agg16(const int* __restrict__ src, const int* __restrict__ dst,
                        const float* __restrict__ hs1, float* __restrict__ acc1,
                        int ne) {
    long long tid = (long long)blockIdx.x * blockDim.x + threadIdx.x;
    int e = (int)(tid >> 4);
    int f = (int)(tid & 15);
    if (e >= ne) return;
    int s = src[e];
    int d = dst[e];
    atomicAdd(&acc1[(size_t)d * N_HID + f], hs1[(size_t)s * N_HID + f]);
}

// per-node: v = relu(dis*acc1 + b1); h2 = v @ W2; hs2 = h2*dis; acc2 = hs2
__global__ void k_layer2(const float* __restrict__ dis, const float* __restrict__ acc1,
                         const float* __restrict__ b1, const float* __restrict__ W2,
                         float* __restrict__ hs2, float* __restrict__ acc2, int n) {
    int i = blockIdx.x * blockDim.x + threadIdx.x;
    if (i >= n) return;
    float di = dis[i];
    const float* ac = acc1 + (size_t)i * N_HID;
    float h2a = 0.0f, h2b = 0.0f;
#pragma unroll
    for (int f = 0; f < N_HID; ++f) {
        float v = fmaf(di, ac[f], b1[f]);
        v = fmaxf(v, 0.0f);
        h2a = fmaf(v, W2[f * N_OUT + 0], h2a);
        h2b = fmaf(v, W2[f * N_OUT + 1], h2b);
    }
    float a = h2a * di;
    float b = h2b * di;
    hs2[(size_t)i * N_OUT + 0] = a;
    hs2[(size_t)i * N_OUT + 1] = b;
    acc2[(size_t)i * N_OUT + 0] = a;
    acc2[(size_t)i * N_OUT + 1] = b;
}

// per-(edge, c): acc2[dst*2+c] += hs2[src*2+c]
__global__ void k_agg2(const int* __restrict__ src, const int* __restrict__ dst,
                       const float* __restrict__ hs2, float* __restrict__ acc2,
                       int ne) {
    long long tid = (long long)blockIdx.x * blockDim.x + threadIdx.x;
    int e = (int)(tid >> 1);
    int c = (int)(tid & 1);
    if (e >= ne) return;
    int s = src[e];
    int d = dst[e];
    atomicAdd(&acc2[(size_t)d * N_OUT + c], hs2[(size_t)s * N_OUT + c]);
}

// per-node: pre = dis*acc2 + b2; out = log_softmax(pre) over 2 classes
__global__ void k_out(const float* __restrict__ dis, const float* __restrict__ acc2,
                      const float* __restrict__ b2, float* __restrict__ out, int n) {
    int i = blockIdx.x * blockDim.x + threadIdx.x;
    if (i >= n) return;
    float di = dis[i];
    float a = fmaf(di, acc2[(size_t)i * N_OUT + 0], b2[0]);
    float b = fmaf(di, acc2[(size_t)i * N_OUT + 1], b2[1]);
    float m = fmaxf(a, b);
    float lse = m + logf(expf(a - m) + expf(b - m));
    out[(size_t)i * N_OUT + 0] = a - lse;
    out[(size_t)i * N_OUT + 1] = b - lse;
}

// ---------------- launch ----------------

extern "C" void kernel_launch(void* const* d_in, const int* in_sizes, int n_in,
                              void* d_out, int out_size, void* d_ws, size_t ws_size,
                              hipStream_t stream) {
    const float* x  = (const float*)d_in[0];
    const int*   ei = (const int*)d_in[1];
    const float* W1 = (const float*)d_in[2];
    const float* b1 = (const float*)d_in[3];
    const float* W2 = (const float*)d_in[4];
    const float* b2 = (const float*)d_in[5];
    float* out = (float*)d_out;

    const int n  = in_sizes[0] / N_IN_F;   // 200000
    const int ne = in_sizes[1] / 2;        // 6400000
    const int* src = ei;                   // edge_index[0]
    const int* dst = ei + ne;              // edge_index[1]

    // workspace layout (floats)
    float* ws = (float*)d_ws;
    float* deg_dis = ws;                         // n
    float* hs1  = deg_dis + n;                   // n*16
    float* acc1 = hs1 + (size_t)n * N_HID;       // n*16
    float* hs2  = acc1 + (size_t)n * N_HID;      // n*2
    float* acc2 = hs2 + (size_t)n * N_OUT;       // n*2

    const int B = 256;
    dim3 blk(B);

    // 1. deg = 1 (self-loops)
    k_init_deg<<<dim3((n + B - 1) / B), blk, 0, stream>>>(deg_dis, n);
    // 2. deg[dst] += 1 per edge
    k_deg<<<dim3((ne + B - 1) / B), blk, 0, stream>>>(dst, deg_dis, ne);
    // 3. dis, h1, hs1, acc1 seed
    k_h1<<<dim3((n + B - 1) / B), blk, 0, stream>>>(x, W1, deg_dis, hs1, acc1, n);
    // 4. layer-1 scatter-add, 16 threads per edge
    {
        long long total = (long long)ne * N_HID;
        long long nb = (total + B - 1) / B;
        k_agg16<<<dim3((unsigned)nb), blk, 0, stream>>>(src, dst, hs1, acc1, ne);
    }
    // 5. layer 2 transform
    k_layer2<<<dim3((n + B - 1) / B), blk, 0, stream>>>(deg_dis, acc1, b1, W2, hs2, acc2, n);
    // 6. layer-2 scatter-add, 2 threads per edge
    {
        long long total = (long long)ne * N_OUT;
        long long nb = (total + B - 1) / B;
        k_agg2<<<dim3((unsigned)nb), blk, 0, stream>>>(src, dst, hs2, acc2, ne);
    }
    // 7. log-softmax epilogue
    k_out<<<dim3((n + B - 1) / B), blk, 0, stream>>>(deg_dis, acc2, b2, out, n);
}